// Round 7
// baseline (104.133 us; speedup 1.0000x reference)
//
#include <hip/hip_runtime.h>

#define NROWS 2048
#define MLEN  3000
#define LPAD  4096
#define PAD0  548
#define NLVL  8

union F4 { float4 v; float f[4]; };

// Wave-local LDS visibility: every producer/consumer is this wave.
__device__ inline void wave_fence() {
    asm volatile("s_waitcnt lgkmcnt(0)" ::: "memory");
}

// R11: ONE WAVE PER ROW, zero block-level synchronization.
// NT=64, grid=2048; per-row LDS A[2048]+B[1024]+CS[512] = 14.3 KB ->
// 8 single-wave blocks/CU. All 15 level transitions are wave-local
// lgkmcnt fences. d1/d2 mirrors dropped: synth1/synth2 read details back
// from crow (L2-warm, same CU), guarded by one wave-local vmcnt(0) drain.
// Per-lane work per phase is 4x the old per-thread work (8 windows at
// lvl0, 8 items at synth0) -> deep independent load/FMA streams for the
// scheduler instead of one tiny latency ladder per phase.
// Buffer plan (ping-pong, analysis): a0->A[0..2048) split ev|od,
// a1->B[0..1024), a2->A[0..512), a3->B[0..256), a4->A[0..128),
// a5->B[0..64), a6->A[0..32), a7(final16)->CS[496..512)+crow tail.
// d3..d7 -> CS[0..496) (as before). Synthesis: s7->A[0..32), s6->B[0..64),
// s5->A[0..128), s4->B[0..256), s3->A[0..512), s2->B[0..1024) (d2 from
// global), s1->A[0..2048) (d1 from global), s0->recon (d0 from global).
// Every write region's previous tenant is dead >=2 levels earlier.
__global__ __launch_bounds__(64, 2) void despawn_kernel(
    const float* __restrict__ x,
    const float* __restrict__ scaling,
    const float* __restrict__ scaling_rec,
    float* __restrict__ recon_out,
    float* __restrict__ coef_out)
{
    __shared__ __align__(16) float A[2048];
    __shared__ __align__(16) float B[1024];
    __shared__ __align__(16) float CS[512];

    const int t   = threadIdx.x;          // 0..63, one wave
    const int row = blockIdx.x;
    float* const crow = coef_out + (size_t)row * LPAD;
    const float* xr = x + (size_t)row * MLEN;

    // ---------------- analysis level 0 : 8 windows per lane ----------------
    // out[j] = sum_k x_pad[(2j-k) mod 4096] f[k]; x_pad[i]=xr[clamp(i-548)],
    // i<0 wraps to hi pad (all wrap targets clamp to xr[2999]).
    {
        float S[8], Wr[8];
#pragma unroll
        for (int k = 0; k < 8; ++k) { S[k] = scaling[k]; Wr[k] = scaling_rec[7 - k]; }
        for (int it = 0; it < 8; ++it) {
            const int g  = t + (it << 6);          // item 0..511
            const int n0 = (g << 3) - 8;           // first natural of window
            F4 V0, V1, V2, V3;
            if (n0 >= PAD0 && n0 + 15 <= PAD0 + MLEN - 1) {
                const float4* src = reinterpret_cast<const float4*>(xr + (n0 - PAD0));
                V0.v = src[0]; V1.v = src[1]; V2.v = src[2]; V3.v = src[3];
            } else {
                const float x0  = xr[0];
                const float xhi = xr[MLEN - 1];
#pragma unroll
                for (int j = 0; j < 16; ++j) {
                    const int n = n0 + j;
                    const int m = (n < 0) ? n + LPAD : n;   // wrap region is all >= 3548
                    float val;
                    if (m < PAD0)              val = x0;
                    else if (m >= PAD0 + MLEN) val = xhi;
                    else                       val = xr[m - PAD0];
                    if (j < 4)       V0.f[j & 3] = val;
                    else if (j < 8)  V1.f[j & 3] = val;
                    else if (j < 12) V2.f[j & 3] = val;
                    else             V3.f[j & 3] = val;
                }
            }
            float e[8] = {V0.f[0],V0.f[2],V1.f[0],V1.f[2],V2.f[0],V2.f[2],V3.f[0],V3.f[2]};
            float o[8] = {V0.f[1],V0.f[3],V1.f[1],V1.f[3],V2.f[1],V2.f[3],V3.f[1],V3.f[3]};
            float ds[4], as[4];
#pragma unroll
            for (int u = 0; u < 4; ++u) {
                float d = 0.f, a = 0.f;
#pragma unroll
                for (int m = 0; m < 4; ++m) {
                    const float vE = e[4 + u - m];
                    const float vO = o[3 + u - m];
                    d = fmaf(vE, Wr[2 * m], d);
                    d = fmaf(vO, -Wr[2 * m + 1], d);
                    a = fmaf(vE, S[2 * m], a);
                    a = fmaf(vO, S[2 * m + 1], a);
                }
                ds[u] = d; as[u] = a;
            }
            F4 dv; dv.f[0] = ds[0]; dv.f[1] = ds[1]; dv.f[2] = ds[2]; dv.f[3] = ds[3];
            reinterpret_cast<float4*>(crow)[g] = dv.v;           // details0 -> global
            *reinterpret_cast<float2*>(A + 2 * g)        = make_float2(as[0], as[2]);
            *reinterpret_cast<float2*>(A + 1024 + 2 * g) = make_float2(as[1], as[3]);
        }
    }
    wave_fence();

    // ---------------- analysis levels 1..7 : wave-local ping-pong ----------------
    {
        float* cur = A;
        float* alt = B;
        int H = 1024;            // output count of this level
        int coff = 2048;
        for (int lvl = 1; lvl < NLVL; ++lvl) {
            float S[8], Wr[8];
#pragma unroll
            for (int k = 0; k < 8; ++k) {
                S[k]  = scaling[lvl * 8 + k];
                Wr[k] = scaling_rec[lvl * 8 + 7 - k];
            }
            const int q = H >> 2;
            const int qm = q - 1;
            const float4* ev4 = reinterpret_cast<const float4*>(cur);
            const float4* od4 = reinterpret_cast<const float4*>(cur + H);
            float4* dst4 = reinterpret_cast<float4*>(crow + coff);
            float4* mir4 = reinterpret_cast<float4*>(CS + (coff - 3584)); // valid lvl>=3
            for (int g = t; g < q; g += 64) {
                F4 Ea, Eb, Oa, Ob;
                Ea.v = ev4[(g - 1) & qm];
                Eb.v = ev4[g];
                Oa.v = od4[(g - 1) & qm];
                Ob.v = od4[g];
                float e[8] = {Ea.f[0],Ea.f[1],Ea.f[2],Ea.f[3],Eb.f[0],Eb.f[1],Eb.f[2],Eb.f[3]};
                float o[8] = {Oa.f[0],Oa.f[1],Oa.f[2],Oa.f[3],Ob.f[0],Ob.f[1],Ob.f[2],Ob.f[3]};
                float ds[4], as[4];
#pragma unroll
                for (int u = 0; u < 4; ++u) {
                    float d = 0.f, a = 0.f;
#pragma unroll
                    for (int m = 0; m < 4; ++m) {
                        const float vE = e[4 + u - m];
                        const float vO = o[3 + u - m];
                        d = fmaf(vE, Wr[2 * m], d);
                        d = fmaf(vO, -Wr[2 * m + 1], d);
                        a = fmaf(vE, S[2 * m], a);
                        a = fmaf(vO, S[2 * m + 1], a);
                    }
                    ds[u] = d; as[u] = a;
                }
                F4 dv; dv.f[0] = ds[0]; dv.f[1] = ds[1]; dv.f[2] = ds[2]; dv.f[3] = ds[3];
                dst4[g] = dv.v;                  // details -> global coeffs
                if (lvl >= 3) mir4[g] = dv.v;    // d3..d7 -> CS mirror
                if (lvl < NLVL - 1) {
                    *reinterpret_cast<float2*>(alt + 2 * g)            = make_float2(as[0], as[2]);
                    *reinterpret_cast<float2*>(alt + (H >> 1) + 2 * g) = make_float2(as[1], as[3]);
                } else {
                    // final approx, natural order (as[u] = approx[4g+u])
                    F4 av; av.f[0] = as[0]; av.f[1] = as[1]; av.f[2] = as[2]; av.f[3] = as[3];
                    *reinterpret_cast<float4*>(CS + 496 + 4 * g)          = av.v;
                    *reinterpret_cast<float4*>(crow + LPAD - 16 + 4 * g)  = av.v;
                }
            }
            wave_fence();
            coff += H;
            float* tmp = cur; cur = alt; alt = tmp;
            H >>= 1;
        }
    }

    // ---------------- synthesis levels 7..3 : CS details, wave-local ----------------
    // out[n] = sum_{k≡n mod 2} d[((n+p)/2+m)&lm]*wav[k] + a[..]*sca[k], k=p+2m
    const float* a = CS + 496;
    float* obuf = A;             // 32->A, 64->B, 128->A, 256->B, 512->A
    int len = 16;
    for (int lvl = NLVL - 1; lvl >= 3; --lvl) {
        float S[8], Wr[8];
#pragma unroll
        for (int k = 0; k < 8; ++k) {
            S[k]  = scaling[lvl * 8 + k];
            Wr[k] = scaling_rec[lvl * 8 + 7 - k];
        }
        const int Mout = len << 1;
        const int doff = LPAD - (LPAD >> lvl);
        const float4* d4 = reinterpret_cast<const float4*>(CS + (doff - 3584));
        const float4* a4 = reinterpret_cast<const float4*>(a);
        const int gq = Mout >> 3;
        const int fm = (len >> 2) - 1;
        for (int g = t; g < gq; g += 64) {
            F4 Da, Db, Aa, Ab;
            Da.v = d4[g]; Db.v = d4[(g + 1) & fm];
            Aa.v = a4[g]; Ab.v = a4[(g + 1) & fm];
            float dd[8] = {Da.f[0],Da.f[1],Da.f[2],Da.f[3],Db.f[0],Db.f[1],Db.f[2],Db.f[3]};
            float aa[8] = {Aa.f[0],Aa.f[1],Aa.f[2],Aa.f[3],Ab.f[0],Ab.f[1],Ab.f[2],Ab.f[3]};
            float out[8];
#pragma unroll
            for (int u = 0; u < 8; ++u) {
                const int p = u & 1, c = (u + 1) >> 1;
                float s = 0.f;
#pragma unroll
                for (int m = 0; m < 4; ++m) {
                    const float w = Wr[p + 2 * m];
                    s = fmaf(dd[c + m], p ? -w : w, s);
                    s = fmaf(aa[c + m], S[p + 2 * m], s);
                }
                out[u] = s;
            }
            F4 o0, o1;
            o0.f[0] = out[0]; o0.f[1] = out[1]; o0.f[2] = out[2]; o0.f[3] = out[3];
            o1.f[0] = out[4]; o1.f[1] = out[5]; o1.f[2] = out[6]; o1.f[3] = out[7];
            float4* ob4 = reinterpret_cast<float4*>(obuf + 8 * g);
            ob4[0] = o0.v; ob4[1] = o1.v;
        }
        wave_fence();
        a = obuf;
        obuf = (obuf == A) ? B : A;
        len = Mout;
    }
    // a == A (512-approx), obuf == B, len == 512

    // Drain this wave's coef stores (d0/d1/d2 written long ago) before the
    // global readbacks; wave-local, same-CU L2 -> coherent.
    asm volatile("s_waitcnt vmcnt(0)" ::: "memory");

    // ---------------- synthesis level 2 : d2 from global, out 1024 -> B ----------------
    {
        float S[8], Wr[8];
#pragma unroll
        for (int k = 0; k < 8; ++k) {
            S[k]  = scaling[2 * 8 + k];
            Wr[k] = scaling_rec[2 * 8 + 7 - k];
        }
        const float4* d4 = reinterpret_cast<const float4*>(crow + 3072);  // d2 (512)
        const float4* a4 = reinterpret_cast<const float4*>(a);            // A, 512
        const int fm = 127;
        for (int g = t; g < 128; g += 64) {
            F4 Da, Db, Aa, Ab;
            Da.v = d4[g]; Db.v = d4[(g + 1) & fm];
            Aa.v = a4[g]; Ab.v = a4[(g + 1) & fm];
            float dd[8] = {Da.f[0],Da.f[1],Da.f[2],Da.f[3],Db.f[0],Db.f[1],Db.f[2],Db.f[3]};
            float aa[8] = {Aa.f[0],Aa.f[1],Aa.f[2],Aa.f[3],Ab.f[0],Ab.f[1],Ab.f[2],Ab.f[3]};
            float out[8];
#pragma unroll
            for (int u = 0; u < 8; ++u) {
                const int p = u & 1, c = (u + 1) >> 1;
                float s = 0.f;
#pragma unroll
                for (int m = 0; m < 4; ++m) {
                    const float w = Wr[p + 2 * m];
                    s = fmaf(dd[c + m], p ? -w : w, s);
                    s = fmaf(aa[c + m], S[p + 2 * m], s);
                }
                out[u] = s;
            }
            F4 o0, o1;
            o0.f[0] = out[0]; o0.f[1] = out[1]; o0.f[2] = out[2]; o0.f[3] = out[3];
            o1.f[0] = out[4]; o1.f[1] = out[5]; o1.f[2] = out[6]; o1.f[3] = out[7];
            float4* ob4 = reinterpret_cast<float4*>(B + 8 * g);
            ob4[0] = o0.v; ob4[1] = o1.v;
        }
    }
    wave_fence();

    // ---------------- synthesis level 1 : d1 from global, out 2048 -> A ----------------
    {
        float S[8], Wr[8];
#pragma unroll
        for (int k = 0; k < 8; ++k) {
            S[k]  = scaling[1 * 8 + k];
            Wr[k] = scaling_rec[1 * 8 + 7 - k];
        }
        const float4* d4 = reinterpret_cast<const float4*>(crow + 2048);  // d1 (1024)
        const float4* a4 = reinterpret_cast<const float4*>(B);            // 1024
        const int fm = 255;
        for (int g = t; g < 256; g += 64) {
            F4 Da, Db, Aa, Ab;
            Da.v = d4[g]; Db.v = d4[(g + 1) & fm];
            Aa.v = a4[g]; Ab.v = a4[(g + 1) & fm];
            float dd[8] = {Da.f[0],Da.f[1],Da.f[2],Da.f[3],Db.f[0],Db.f[1],Db.f[2],Db.f[3]};
            float aa[8] = {Aa.f[0],Aa.f[1],Aa.f[2],Aa.f[3],Ab.f[0],Ab.f[1],Ab.f[2],Ab.f[3]};
            float out[8];
#pragma unroll
            for (int u = 0; u < 8; ++u) {
                const int p = u & 1, c = (u + 1) >> 1;
                float s = 0.f;
#pragma unroll
                for (int m = 0; m < 4; ++m) {
                    const float w = Wr[p + 2 * m];
                    s = fmaf(dd[c + m], p ? -w : w, s);
                    s = fmaf(aa[c + m], S[p + 2 * m], s);
                }
                out[u] = s;
            }
            F4 o0, o1;
            o0.f[0] = out[0]; o0.f[1] = out[1]; o0.f[2] = out[2]; o0.f[3] = out[3];
            o1.f[0] = out[4]; o1.f[1] = out[5]; o1.f[2] = out[6]; o1.f[3] = out[7];
            float4* ob4 = reinterpret_cast<float4*>(A + 8 * g);
            ob4[0] = o0.v; ob4[1] = o1.v;
        }
    }
    wave_fence();

    // ---------------- synthesis level 0 : d0 from global, straight to recon ----------------
    {
        float S[8], Wr[8];
#pragma unroll
        for (int k = 0; k < 8; ++k) { S[k] = scaling[k]; Wr[k] = scaling_rec[7 - k]; }
        const float4* d4 = reinterpret_cast<const float4*>(crow);   // details0 (L2-warm)
        const float4* a4 = reinterpret_cast<const float4*>(A);      // 2048 approx
        const int fm = 511;
        float* const ro = recon_out + (size_t)row * MLEN;
        for (int g = t; g < (LPAD >> 3); g += 64) {
            F4 Da, Db, Aa, Ab;
            Da.v = d4[g]; Db.v = d4[(g + 1) & fm];
            Aa.v = a4[g]; Ab.v = a4[(g + 1) & fm];
            float dd[8] = {Da.f[0],Da.f[1],Da.f[2],Da.f[3],Db.f[0],Db.f[1],Db.f[2],Db.f[3]};
            float aa[8] = {Aa.f[0],Aa.f[1],Aa.f[2],Aa.f[3],Ab.f[0],Ab.f[1],Ab.f[2],Ab.f[3]};
            float out[8];
#pragma unroll
            for (int u = 0; u < 8; ++u) {
                const int p = u & 1, c = (u + 1) >> 1;
                float s = 0.f;
#pragma unroll
                for (int m = 0; m < 4; ++m) {
                    const float w = Wr[p + 2 * m];
                    s = fmaf(dd[c + m], p ? -w : w, s);
                    s = fmaf(aa[c + m], S[p + 2 * m], s);
                }
                out[u] = s;
            }
            const int n0 = 8 * g;
            if (n0 >= PAD0 && n0 + 8 <= PAD0 + MLEN) {
                F4 o0, o1;
                o0.f[0] = out[0]; o0.f[1] = out[1]; o0.f[2] = out[2]; o0.f[3] = out[3];
                o1.f[0] = out[4]; o1.f[1] = out[5]; o1.f[2] = out[6]; o1.f[3] = out[7];
                float4* r4 = reinterpret_cast<float4*>(ro + (n0 - PAD0));
                r4[0] = o0.v; r4[1] = o1.v;
            } else {
#pragma unroll
                for (int u = 0; u < 8; ++u) {
                    const int n = n0 + u;
                    if (n >= PAD0 && n < PAD0 + MLEN) ro[n - PAD0] = out[u];
                }
            }
        }
    }
}

extern "C" void kernel_launch(void* const* d_in, const int* in_sizes, int n_in,
                              void* d_out, int out_size, void* d_ws, size_t ws_size,
                              hipStream_t stream) {
    const float* x           = (const float*)d_in[0];
    const float* scaling     = (const float*)d_in[1];
    const float* scaling_rec = (const float*)d_in[2];
    float* recon = (float*)d_out;                       // 2048*3000 floats
    float* coefo = recon + (size_t)NROWS * MLEN;        // 2048*4096 floats
    despawn_kernel<<<dim3(NROWS), dim3(64), 0, stream>>>(x, scaling, scaling_rec,
                                                         recon, coefo);
    (void)in_sizes; (void)n_in; (void)out_size; (void)d_ws; (void)ws_size;
}

// Round 8
// 96.920 us; speedup vs baseline: 1.0744x; 1.0744x over previous
//
#include <hip/hip_runtime.h>

#define NROWS 2048
#define MLEN  3000
#define LPAD  4096
#define PAD0  548
#define NLVL  8
#define NT    512
#define RPB   2

union F4 { float4 v; float f[4]; };

// Light barrier: LDS-visibility only (s_waitcnt lgkmcnt(0) + s_barrier).
// Does NOT drain vmcnt, so details->global write-through stays in flight
// across analysis level boundaries.
__device__ inline void lds_barrier() {
    asm volatile("s_waitcnt lgkmcnt(0)\n\ts_barrier" ::: "memory");
}

// Best-measured configuration (R9, 95.27 us), stagger removed (R12).
// R6: s_setprio(1) around FMA bursts.
// R7: filters in SGPRs (s_load from global at wave-uniform indices; wavelet
//     sign folded into fmaf neg modifier, 7-k reversal into indexing).
// R8: analysis lvl0 reads x directly from global (4x dwordx4/thread,
//     in-register even/odd deinterleave); final-approx repack folded into lvl7.
// R9: two rows per block (NT=512, 4 blocks/CU x 8 waves = 32 waves/CU).
// R12: XCD-stagger sleep removed — R9/R10 falsified the barrier-lockstep
//     theory it served; it was pure startup overhead for 3/4 of blocks.
// Session nulls (kept out): barrier-free middle (R10, +2us), one-wave-per-row
// (R11, +9us: occupancy is the binding resource at 32 waves/CU).
__global__ __launch_bounds__(NT, 8) void despawn_kernel(
    const float* __restrict__ x,
    const float* __restrict__ scaling,
    const float* __restrict__ scaling_rec,
    float* __restrict__ recon_out,
    float* __restrict__ coef_out)
{
    // per row: SA 2048 | SB 2112 | CS 512  (4672 floats = 18688 B)
    __shared__ __align__(16) float LDSBUF[RPB][4672];

    const int tid = threadIdx.x;
    const int r   = tid >> 8;        // row slot within block
    const int t   = tid & 255;       // lane within row pipeline
    const int row = blockIdx.x * RPB + r;
    float* const sa = &LDSBUF[r][0];
    float* const sb = &LDSBUF[r][2048];
    float* const cs = &LDSBUF[r][4160];

    float* const crow = coef_out + (size_t)row * LPAD;
    const float* xr = x + (size_t)row * MLEN;

    // ---------------- analysis level 0 : direct from global ----------------
    // out[j] = sum_k x_pad[(2j-k) mod 4096] f[k]; x_pad[i]=xr[clamp(i-548)],
    // i<0 wraps to hi pad (also clamps to xr[2999]).
    // Thread t, half h needs naturals [2j0+8t-8, 2j0+8t+7] (16B-aligned in xr).
    {
        float S[8], Wr[8];
#pragma unroll
        for (int k = 0; k < 8; ++k) { S[k] = scaling[k]; Wr[k] = scaling_rec[7 - k]; }
#pragma unroll
        for (int h = 0; h < 2; ++h) {
            const int j0 = 1024 * h;
            const int n0 = 2 * j0 + 8 * t - 8;
            F4 V0, V1, V2, V3;
            if (n0 >= PAD0 && n0 + 15 <= PAD0 + MLEN - 1) {
                const float4* src = reinterpret_cast<const float4*>(xr + (n0 - PAD0));
                V0.v = src[0]; V1.v = src[1]; V2.v = src[2]; V3.v = src[3];
            } else {
                const float x0  = xr[0];
                const float xhi = xr[MLEN - 1];
#pragma unroll
                for (int j = 0; j < 16; ++j) {
                    const int n = n0 + j;
                    const int m = (n < 0) ? n + LPAD : n;   // wrap region is all >= 3548
                    float val;
                    if (m < PAD0)              val = x0;
                    else if (m >= PAD0 + MLEN) val = xhi;
                    else                       val = xr[m - PAD0];
                    if (j < 4)       V0.f[j & 3] = val;
                    else if (j < 8)  V1.f[j & 3] = val;
                    else if (j < 12) V2.f[j & 3] = val;
                    else             V3.f[j & 3] = val;
                }
            }
            float e[8] = {V0.f[0],V0.f[2],V1.f[0],V1.f[2],V2.f[0],V2.f[2],V3.f[0],V3.f[2]};
            float o[8] = {V0.f[1],V0.f[3],V1.f[1],V1.f[3],V2.f[1],V2.f[3],V3.f[1],V3.f[3]};
            float ds[4], as[4];
            __builtin_amdgcn_s_setprio(1);
#pragma unroll
            for (int u = 0; u < 4; ++u) {
                float d = 0.f, a = 0.f;
#pragma unroll
                for (int m = 0; m < 4; ++m) {
                    const float vE = e[4 + u - m];
                    const float vO = o[3 + u - m];
                    d = fmaf(vE, Wr[2 * m], d);
                    d = fmaf(vO, -Wr[2 * m + 1], d);
                    a = fmaf(vE, S[2 * m], a);
                    a = fmaf(vO, S[2 * m + 1], a);
                }
                ds[u] = d; as[u] = a;
            }
            __builtin_amdgcn_s_setprio(0);
            F4 dv; dv.f[0] = ds[0]; dv.f[1] = ds[1]; dv.f[2] = ds[2]; dv.f[3] = ds[3];
            reinterpret_cast<float4*>(crow + j0)[t] = dv.v;      // details0 -> global
            *reinterpret_cast<float2*>(sa + (j0 >> 1) + 2 * t)        = make_float2(as[0], as[2]);
            *reinterpret_cast<float2*>(sa + 1024 + (j0 >> 1) + 2 * t) = make_float2(as[1], as[3]);
        }
    }
    lds_barrier();   // sa (approx0, split ev|od) complete for both rows

    // ---------------- analysis levels 1..7 : LDS ping-pong ----------------
    {
        float* cur = sa;
        float* alt = sb;
        int H = 1024;
        int coff = 2048;
        for (int lvl = 1; lvl < NLVL; ++lvl) {
            float S[8], Wr[8];
#pragma unroll
            for (int k = 0; k < 8; ++k) {
                S[k]  = scaling[lvl * 8 + k];
                Wr[k] = scaling_rec[lvl * 8 + 7 - k];
            }
            const int q = H >> 2;
            const int qm = q - 1;
            const float4* ev4 = reinterpret_cast<const float4*>(cur);
            const float4* od4 = reinterpret_cast<const float4*>(cur + H);
            float4* dst4 = reinterpret_cast<float4*>(crow + coff);
            float4* mir4 = (lvl == 1) ? reinterpret_cast<float4*>(sb + 1088)
                         : (lvl == 2) ? reinterpret_cast<float4*>(sa + 512)
                                      : reinterpret_cast<float4*>(cs + (coff - 3584));
            for (int tt = t; tt < q; tt += 256) {
                F4 Ea, Eb, Oa, Ob;
                Ea.v = ev4[(tt - 1) & qm];
                Eb.v = ev4[tt];
                Oa.v = od4[(tt - 1) & qm];
                Ob.v = od4[tt];
                float e[8] = {Ea.f[0],Ea.f[1],Ea.f[2],Ea.f[3],Eb.f[0],Eb.f[1],Eb.f[2],Eb.f[3]};
                float o[8] = {Oa.f[0],Oa.f[1],Oa.f[2],Oa.f[3],Ob.f[0],Ob.f[1],Ob.f[2],Ob.f[3]};
                float ds[4], as[4];
                __builtin_amdgcn_s_setprio(1);
#pragma unroll
                for (int u = 0; u < 4; ++u) {
                    float d = 0.f, a = 0.f;
#pragma unroll
                    for (int m = 0; m < 4; ++m) {
                        const float vE = e[4 + u - m];
                        const float vO = o[3 + u - m];
                        d = fmaf(vE, Wr[2 * m], d);
                        d = fmaf(vO, -Wr[2 * m + 1], d);
                        a = fmaf(vE, S[2 * m], a);
                        a = fmaf(vO, S[2 * m + 1], a);
                    }
                    ds[u] = d; as[u] = a;
                }
                __builtin_amdgcn_s_setprio(0);
                F4 dv; dv.f[0] = ds[0]; dv.f[1] = ds[1]; dv.f[2] = ds[2]; dv.f[3] = ds[3];
                dst4[tt] = dv.v;     // details -> global (coeffs output), not drained
                mir4[tt] = dv.v;     // details -> LDS mirror for synthesis
                if (lvl < NLVL - 1) {
                    *reinterpret_cast<float2*>(alt + 2 * tt)            = make_float2(as[0], as[2]);
                    *reinterpret_cast<float2*>(alt + (H >> 1) + 2 * tt) = make_float2(as[1], as[3]);
                } else {
                    // final approx in natural order (as[u]=approx[4tt+u])
                    F4 av; av.f[0] = as[0]; av.f[1] = as[1]; av.f[2] = as[2]; av.f[3] = as[3];
                    *reinterpret_cast<float4*>(cs + 496 + 4 * tt)         = av.v;
                    *reinterpret_cast<float4*>(crow + LPAD - 16 + 4 * tt) = av.v;
                }
            }
            lds_barrier();
            coff += H;
            float* tmp = cur; cur = alt; alt = tmp;
            H >>= 1;
        }
    }

    // FULL sync: drains every wave's crow stores before synthesis's global
    // readback of details0 (the one place vmcnt(0) is semantically required).
    __syncthreads();

    // ---------------- synthesis levels 7..1 (all-LDS) ----------------
    // out[n] = sum_{k≡n mod 2} d[((n+p)/2+m)&lm]*wav[k] + a[..]*sca[k], k=p+2m
    // wav sign (-1)^k with k=p+2m -> (p ? -1 : +1), folded per-u.
    const float* a = cs + 496;
    float* obuf = sa;   // 32->sa,64->sb,128->sa,256->sb,512->sa,1024->sb,2048->sa
    int len = 16;
    for (int lvl = NLVL - 1; lvl >= 1; --lvl) {
        float S[8], Wr[8];
#pragma unroll
        for (int k = 0; k < 8; ++k) {
            S[k]  = scaling[lvl * 8 + k];
            Wr[k] = scaling_rec[lvl * 8 + 7 - k];
        }
        const int Mout = len << 1;
        const int doff = LPAD - (LPAD >> lvl);
        const float4* d4 = (lvl >= 3) ? reinterpret_cast<const float4*>(cs + (doff - 3584))
                         : (lvl == 2) ? reinterpret_cast<const float4*>(sa + 512)
                                      : reinterpret_cast<const float4*>(sb + 1088);
        const float4* a4 = reinterpret_cast<const float4*>(a);
        const int gq = Mout >> 3;     // 8 outputs per work item
        const int fm = (len >> 2) - 1;
        for (int g = t; g < gq; g += 256) {
            F4 Da, Db, Aa, Ab;
            Da.v = d4[g]; Db.v = d4[(g + 1) & fm];
            Aa.v = a4[g]; Ab.v = a4[(g + 1) & fm];
            float dd[8] = {Da.f[0],Da.f[1],Da.f[2],Da.f[3],Db.f[0],Db.f[1],Db.f[2],Db.f[3]};
            float aa[8] = {Aa.f[0],Aa.f[1],Aa.f[2],Aa.f[3],Ab.f[0],Ab.f[1],Ab.f[2],Ab.f[3]};
            float out[8];
            __builtin_amdgcn_s_setprio(1);
#pragma unroll
            for (int u = 0; u < 8; ++u) {
                const int p = u & 1, c = (u + 1) >> 1;
                float s = 0.f;
#pragma unroll
                for (int m = 0; m < 4; ++m) {
                    const float w = Wr[p + 2 * m];
                    s = fmaf(dd[c + m], p ? -w : w, s);
                    s = fmaf(aa[c + m], S[p + 2 * m], s);
                }
                out[u] = s;
            }
            __builtin_amdgcn_s_setprio(0);
            F4 o0, o1;
            o0.f[0] = out[0]; o0.f[1] = out[1]; o0.f[2] = out[2]; o0.f[3] = out[3];
            o1.f[0] = out[4]; o1.f[1] = out[5]; o1.f[2] = out[6]; o1.f[3] = out[7];
            float4* ob4 = reinterpret_cast<float4*>(obuf + 8 * g);
            ob4[0] = o0.v; ob4[1] = o1.v;
        }
        lds_barrier();
        a = obuf;
        obuf = (obuf == sa) ? sb : sa;
        len = Mout;
    }
    // a == sa (2048 approx)

    // ---------------- synthesis level 0 : straight to recon ----------------
    {
        float S[8], Wr[8];
#pragma unroll
        for (int k = 0; k < 8; ++k) { S[k] = scaling[k]; Wr[k] = scaling_rec[7 - k]; }
        const float4* d4 = reinterpret_cast<const float4*>(crow);   // details0 (L2-warm)
        const float4* a4 = reinterpret_cast<const float4*>(a);
        const int fm = (len >> 2) - 1;                              // len == 2048
        float* const ro = recon_out + (size_t)row * MLEN;
        for (int g = t; g < (LPAD >> 3); g += 256) {
            F4 Da, Db, Aa, Ab;
            Da.v = d4[g]; Db.v = d4[(g + 1) & fm];
            Aa.v = a4[g]; Ab.v = a4[(g + 1) & fm];
            float dd[8] = {Da.f[0],Da.f[1],Da.f[2],Da.f[3],Db.f[0],Db.f[1],Db.f[2],Db.f[3]};
            float aa[8] = {Aa.f[0],Aa.f[1],Aa.f[2],Aa.f[3],Ab.f[0],Ab.f[1],Ab.f[2],Ab.f[3]};
            float out[8];
            __builtin_amdgcn_s_setprio(1);
#pragma unroll
            for (int u = 0; u < 8; ++u) {
                const int p = u & 1, c = (u + 1) >> 1;
                float s = 0.f;
#pragma unroll
                for (int m = 0; m < 4; ++m) {
                    const float w = Wr[p + 2 * m];
                    s = fmaf(dd[c + m], p ? -w : w, s);
                    s = fmaf(aa[c + m], S[p + 2 * m], s);
                }
                out[u] = s;
            }
            __builtin_amdgcn_s_setprio(0);
            const int n0 = 8 * g;
            if (n0 >= PAD0 && n0 + 8 <= PAD0 + MLEN) {
                F4 o0, o1;
                o0.f[0] = out[0]; o0.f[1] = out[1]; o0.f[2] = out[2]; o0.f[3] = out[3];
                o1.f[0] = out[4]; o1.f[1] = out[5]; o1.f[2] = out[6]; o1.f[3] = out[7];
                float4* r4 = reinterpret_cast<float4*>(ro + (n0 - PAD0));
                r4[0] = o0.v; r4[1] = o1.v;
            } else {
#pragma unroll
                for (int u = 0; u < 8; ++u) {
                    const int n = n0 + u;
                    if (n >= PAD0 && n < PAD0 + MLEN) ro[n - PAD0] = out[u];
                }
            }
        }
    }
}

extern "C" void kernel_launch(void* const* d_in, const int* in_sizes, int n_in,
                              void* d_out, int out_size, void* d_ws, size_t ws_size,
                              hipStream_t stream) {
    const float* x           = (const float*)d_in[0];
    const float* scaling     = (const float*)d_in[1];
    const float* scaling_rec = (const float*)d_in[2];
    float* recon = (float*)d_out;                       // 2048*3000 floats
    float* coefo = recon + (size_t)NROWS * MLEN;        // 2048*4096 floats
    despawn_kernel<<<dim3(NROWS / RPB), dim3(NT), 0, stream>>>(x, scaling, scaling_rec,
                                                               recon, coefo);
    (void)in_sizes; (void)n_in; (void)out_size; (void)d_ws; (void)ws_size;
}

// Round 9
// 94.949 us; speedup vs baseline: 1.0967x; 1.0207x over previous
//
#include <hip/hip_runtime.h>

#define NROWS 2048
#define MLEN  3000
#define LPAD  4096
#define PAD0  548
#define NLVL  8
#define NT    512
#define RPB   2

union F4 { float4 v; float f[4]; };

// Light barrier: LDS-visibility only (s_waitcnt lgkmcnt(0) + s_barrier).
// Does NOT drain vmcnt, so details->global write-through stays in flight
// across analysis level boundaries.
__device__ inline void lds_barrier() {
    asm volatile("s_waitcnt lgkmcnt(0)\n\ts_barrier" ::: "memory");
}

// FINAL: exact best-measured configuration (R9, 95.27 us).
// R6: s_setprio(1) around FMA bursts.
// R7: filters in SGPRs (s_load from global at wave-uniform indices; wavelet
//     sign folded into fmaf neg modifier, 7-k reversal into indexing).
// R8: analysis lvl0 reads x directly from global (4x dwordx4/thread,
//     in-register even/odd deinterleave); final-approx repack folded into lvl7.
// R9: two rows per block (NT=512, 4 blocks/CU x 8 waves = 32 waves/CU).
// XCD stagger RESTORED: R12's A/B (stagger removed, same structure) measured
//     +1.65us — the desync overlap benefit exceeds its one-time startup cost.
// Measured nulls kept out: barrier-free middle (R10, +2.3us), one-wave-per-row
// (R11, +9us: occupancy is the binding resource at 32 waves/CU).
__global__ __launch_bounds__(NT, 8) void despawn_kernel(
    const float* __restrict__ x,
    const float* __restrict__ scaling,
    const float* __restrict__ scaling_rec,
    float* __restrict__ recon_out,
    float* __restrict__ coef_out)
{
    // per row: SA 2048 | SB 2112 | CS 512  (4672 floats = 18688 B)
    __shared__ __align__(16) float LDSBUF[RPB][4672];

    const int tid = threadIdx.x;
    const int r   = tid >> 8;        // row slot within block
    const int t   = tid & 255;       // lane within row pipeline
    const int row = blockIdx.x * RPB + r;
    float* const sa = &LDSBUF[r][0];
    float* const sb = &LDSBUF[r][2048];
    float* const cs = &LDSBUF[r][4160];

    float* const crow = coef_out + (size_t)row * LPAD;
    const float* xr = x + (size_t)row * MLEN;

    // Desync co-resident blocks (consecutive ids round-robin across 8 XCDs).
    // A/B-verified worth ~1.5us (R9 vs R12).
    {
        const int lag = (blockIdx.x >> 3) & 3;
        for (int i = 0; i < lag; ++i) __builtin_amdgcn_s_sleep(8);
    }

    // ---------------- analysis level 0 : direct from global ----------------
    // out[j] = sum_k x_pad[(2j-k) mod 4096] f[k]; x_pad[i]=xr[clamp(i-548)],
    // i<0 wraps to hi pad (also clamps to xr[2999]).
    // Thread t, half h needs naturals [2j0+8t-8, 2j0+8t+7] (16B-aligned in xr).
    {
        float S[8], Wr[8];
#pragma unroll
        for (int k = 0; k < 8; ++k) { S[k] = scaling[k]; Wr[k] = scaling_rec[7 - k]; }
#pragma unroll
        for (int h = 0; h < 2; ++h) {
            const int j0 = 1024 * h;
            const int n0 = 2 * j0 + 8 * t - 8;
            F4 V0, V1, V2, V3;
            if (n0 >= PAD0 && n0 + 15 <= PAD0 + MLEN - 1) {
                const float4* src = reinterpret_cast<const float4*>(xr + (n0 - PAD0));
                V0.v = src[0]; V1.v = src[1]; V2.v = src[2]; V3.v = src[3];
            } else {
                const float x0  = xr[0];
                const float xhi = xr[MLEN - 1];
#pragma unroll
                for (int j = 0; j < 16; ++j) {
                    const int n = n0 + j;
                    const int m = (n < 0) ? n + LPAD : n;   // wrap region is all >= 3548
                    float val;
                    if (m < PAD0)              val = x0;
                    else if (m >= PAD0 + MLEN) val = xhi;
                    else                       val = xr[m - PAD0];
                    if (j < 4)       V0.f[j & 3] = val;
                    else if (j < 8)  V1.f[j & 3] = val;
                    else if (j < 12) V2.f[j & 3] = val;
                    else             V3.f[j & 3] = val;
                }
            }
            float e[8] = {V0.f[0],V0.f[2],V1.f[0],V1.f[2],V2.f[0],V2.f[2],V3.f[0],V3.f[2]};
            float o[8] = {V0.f[1],V0.f[3],V1.f[1],V1.f[3],V2.f[1],V2.f[3],V3.f[1],V3.f[3]};
            float ds[4], as[4];
            __builtin_amdgcn_s_setprio(1);
#pragma unroll
            for (int u = 0; u < 4; ++u) {
                float d = 0.f, a = 0.f;
#pragma unroll
                for (int m = 0; m < 4; ++m) {
                    const float vE = e[4 + u - m];
                    const float vO = o[3 + u - m];
                    d = fmaf(vE, Wr[2 * m], d);
                    d = fmaf(vO, -Wr[2 * m + 1], d);
                    a = fmaf(vE, S[2 * m], a);
                    a = fmaf(vO, S[2 * m + 1], a);
                }
                ds[u] = d; as[u] = a;
            }
            __builtin_amdgcn_s_setprio(0);
            F4 dv; dv.f[0] = ds[0]; dv.f[1] = ds[1]; dv.f[2] = ds[2]; dv.f[3] = ds[3];
            reinterpret_cast<float4*>(crow + j0)[t] = dv.v;      // details0 -> global
            *reinterpret_cast<float2*>(sa + (j0 >> 1) + 2 * t)        = make_float2(as[0], as[2]);
            *reinterpret_cast<float2*>(sa + 1024 + (j0 >> 1) + 2 * t) = make_float2(as[1], as[3]);
        }
    }
    lds_barrier();   // sa (approx0, split ev|od) complete for both rows

    // ---------------- analysis levels 1..7 : LDS ping-pong ----------------
    {
        float* cur = sa;
        float* alt = sb;
        int H = 1024;
        int coff = 2048;
        for (int lvl = 1; lvl < NLVL; ++lvl) {
            float S[8], Wr[8];
#pragma unroll
            for (int k = 0; k < 8; ++k) {
                S[k]  = scaling[lvl * 8 + k];
                Wr[k] = scaling_rec[lvl * 8 + 7 - k];
            }
            const int q = H >> 2;
            const int qm = q - 1;
            const float4* ev4 = reinterpret_cast<const float4*>(cur);
            const float4* od4 = reinterpret_cast<const float4*>(cur + H);
            float4* dst4 = reinterpret_cast<float4*>(crow + coff);
            float4* mir4 = (lvl == 1) ? reinterpret_cast<float4*>(sb + 1088)
                         : (lvl == 2) ? reinterpret_cast<float4*>(sa + 512)
                                      : reinterpret_cast<float4*>(cs + (coff - 3584));
            for (int tt = t; tt < q; tt += 256) {
                F4 Ea, Eb, Oa, Ob;
                Ea.v = ev4[(tt - 1) & qm];
                Eb.v = ev4[tt];
                Oa.v = od4[(tt - 1) & qm];
                Ob.v = od4[tt];
                float e[8] = {Ea.f[0],Ea.f[1],Ea.f[2],Ea.f[3],Eb.f[0],Eb.f[1],Eb.f[2],Eb.f[3]};
                float o[8] = {Oa.f[0],Oa.f[1],Oa.f[2],Oa.f[3],Ob.f[0],Ob.f[1],Ob.f[2],Ob.f[3]};
                float ds[4], as[4];
                __builtin_amdgcn_s_setprio(1);
#pragma unroll
                for (int u = 0; u < 4; ++u) {
                    float d = 0.f, a = 0.f;
#pragma unroll
                    for (int m = 0; m < 4; ++m) {
                        const float vE = e[4 + u - m];
                        const float vO = o[3 + u - m];
                        d = fmaf(vE, Wr[2 * m], d);
                        d = fmaf(vO, -Wr[2 * m + 1], d);
                        a = fmaf(vE, S[2 * m], a);
                        a = fmaf(vO, S[2 * m + 1], a);
                    }
                    ds[u] = d; as[u] = a;
                }
                __builtin_amdgcn_s_setprio(0);
                F4 dv; dv.f[0] = ds[0]; dv.f[1] = ds[1]; dv.f[2] = ds[2]; dv.f[3] = ds[3];
                dst4[tt] = dv.v;     // details -> global (coeffs output), not drained
                mir4[tt] = dv.v;     // details -> LDS mirror for synthesis
                if (lvl < NLVL - 1) {
                    *reinterpret_cast<float2*>(alt + 2 * tt)            = make_float2(as[0], as[2]);
                    *reinterpret_cast<float2*>(alt + (H >> 1) + 2 * tt) = make_float2(as[1], as[3]);
                } else {
                    // final approx in natural order (as[u]=approx[4tt+u])
                    F4 av; av.f[0] = as[0]; av.f[1] = as[1]; av.f[2] = as[2]; av.f[3] = as[3];
                    *reinterpret_cast<float4*>(cs + 496 + 4 * tt)         = av.v;
                    *reinterpret_cast<float4*>(crow + LPAD - 16 + 4 * tt) = av.v;
                }
            }
            lds_barrier();
            coff += H;
            float* tmp = cur; cur = alt; alt = tmp;
            H >>= 1;
        }
    }

    // FULL sync: drains every wave's crow stores before synthesis's global
    // readback of details0 (the one place vmcnt(0) is semantically required).
    __syncthreads();

    // ---------------- synthesis levels 7..1 (all-LDS) ----------------
    // out[n] = sum_{k≡n mod 2} d[((n+p)/2+m)&lm]*wav[k] + a[..]*sca[k], k=p+2m
    // wav sign (-1)^k with k=p+2m -> (p ? -1 : +1), folded per-u.
    const float* a = cs + 496;
    float* obuf = sa;   // 32->sa,64->sb,128->sa,256->sb,512->sa,1024->sb,2048->sa
    int len = 16;
    for (int lvl = NLVL - 1; lvl >= 1; --lvl) {
        float S[8], Wr[8];
#pragma unroll
        for (int k = 0; k < 8; ++k) {
            S[k]  = scaling[lvl * 8 + k];
            Wr[k] = scaling_rec[lvl * 8 + 7 - k];
        }
        const int Mout = len << 1;
        const int doff = LPAD - (LPAD >> lvl);
        const float4* d4 = (lvl >= 3) ? reinterpret_cast<const float4*>(cs + (doff - 3584))
                         : (lvl == 2) ? reinterpret_cast<const float4*>(sa + 512)
                                      : reinterpret_cast<const float4*>(sb + 1088);
        const float4* a4 = reinterpret_cast<const float4*>(a);
        const int gq = Mout >> 3;     // 8 outputs per work item
        const int fm = (len >> 2) - 1;
        for (int g = t; g < gq; g += 256) {
            F4 Da, Db, Aa, Ab;
            Da.v = d4[g]; Db.v = d4[(g + 1) & fm];
            Aa.v = a4[g]; Ab.v = a4[(g + 1) & fm];
            float dd[8] = {Da.f[0],Da.f[1],Da.f[2],Da.f[3],Db.f[0],Db.f[1],Db.f[2],Db.f[3]};
            float aa[8] = {Aa.f[0],Aa.f[1],Aa.f[2],Aa.f[3],Ab.f[0],Ab.f[1],Ab.f[2],Ab.f[3]};
            float out[8];
            __builtin_amdgcn_s_setprio(1);
#pragma unroll
            for (int u = 0; u < 8; ++u) {
                const int p = u & 1, c = (u + 1) >> 1;
                float s = 0.f;
#pragma unroll
                for (int m = 0; m < 4; ++m) {
                    const float w = Wr[p + 2 * m];
                    s = fmaf(dd[c + m], p ? -w : w, s);
                    s = fmaf(aa[c + m], S[p + 2 * m], s);
                }
                out[u] = s;
            }
            __builtin_amdgcn_s_setprio(0);
            F4 o0, o1;
            o0.f[0] = out[0]; o0.f[1] = out[1]; o0.f[2] = out[2]; o0.f[3] = out[3];
            o1.f[0] = out[4]; o1.f[1] = out[5]; o1.f[2] = out[6]; o1.f[3] = out[7];
            float4* ob4 = reinterpret_cast<float4*>(obuf + 8 * g);
            ob4[0] = o0.v; ob4[1] = o1.v;
        }
        lds_barrier();
        a = obuf;
        obuf = (obuf == sa) ? sb : sa;
        len = Mout;
    }
    // a == sa (2048 approx)

    // ---------------- synthesis level 0 : straight to recon ----------------
    {
        float S[8], Wr[8];
#pragma unroll
        for (int k = 0; k < 8; ++k) { S[k] = scaling[k]; Wr[k] = scaling_rec[7 - k]; }
        const float4* d4 = reinterpret_cast<const float4*>(crow);   // details0 (L2-warm)
        const float4* a4 = reinterpret_cast<const float4*>(a);
        const int fm = (len >> 2) - 1;                              // len == 2048
        float* const ro = recon_out + (size_t)row * MLEN;
        for (int g = t; g < (LPAD >> 3); g += 256) {
            F4 Da, Db, Aa, Ab;
            Da.v = d4[g]; Db.v = d4[(g + 1) & fm];
            Aa.v = a4[g]; Ab.v = a4[(g + 1) & fm];
            float dd[8] = {Da.f[0],Da.f[1],Da.f[2],Da.f[3],Db.f[0],Db.f[1],Db.f[2],Db.f[3]};
            float aa[8] = {Aa.f[0],Aa.f[1],Aa.f[2],Aa.f[3],Ab.f[0],Ab.f[1],Ab.f[2],Ab.f[3]};
            float out[8];
            __builtin_amdgcn_s_setprio(1);
#pragma unroll
            for (int u = 0; u < 8; ++u) {
                const int p = u & 1, c = (u + 1) >> 1;
                float s = 0.f;
#pragma unroll
                for (int m = 0; m < 4; ++m) {
                    const float w = Wr[p + 2 * m];
                    s = fmaf(dd[c + m], p ? -w : w, s);
                    s = fmaf(aa[c + m], S[p + 2 * m], s);
                }
                out[u] = s;
            }
            __builtin_amdgcn_s_setprio(0);
            const int n0 = 8 * g;
            if (n0 >= PAD0 && n0 + 8 <= PAD0 + MLEN) {
                F4 o0, o1;
                o0.f[0] = out[0]; o0.f[1] = out[1]; o0.f[2] = out[2]; o0.f[3] = out[3];
                o1.f[0] = out[4]; o1.f[1] = out[5]; o1.f[2] = out[6]; o1.f[3] = out[7];
                float4* r4 = reinterpret_cast<float4*>(ro + (n0 - PAD0));
                r4[0] = o0.v; r4[1] = o1.v;
            } else {
#pragma unroll
                for (int u = 0; u < 8; ++u) {
                    const int n = n0 + u;
                    if (n >= PAD0 && n < PAD0 + MLEN) ro[n - PAD0] = out[u];
                }
            }
        }
    }
}

extern "C" void kernel_launch(void* const* d_in, const int* in_sizes, int n_in,
                              void* d_out, int out_size, void* d_ws, size_t ws_size,
                              hipStream_t stream) {
    const float* x           = (const float*)d_in[0];
    const float* scaling     = (const float*)d_in[1];
    const float* scaling_rec = (const float*)d_in[2];
    float* recon = (float*)d_out;                       // 2048*3000 floats
    float* coefo = recon + (size_t)NROWS * MLEN;        // 2048*4096 floats
    despawn_kernel<<<dim3(NROWS / RPB), dim3(NT), 0, stream>>>(x, scaling, scaling_rec,
                                                               recon, coefo);
    (void)in_sizes; (void)n_in; (void)out_size; (void)d_ws; (void)ws_size;
}